// Round 10
// baseline (274.476 us; speedup 1.0000x reference)
//
#include <hip/hip_runtime.h>
#include <math.h>
#include <stdint.h>

#define N_NODES 50000
#define N_EDGES 800000
#define IN_DIM 64
#define H_HEADS 4
#define D_HEAD 16
#define NT_TYPES 2
#define ET_TYPES 2
#define HD 64
#define NB_SCAN ((N_NODES + 255) / 256)   // 196
#define M_COLS 320                         // 64 q + 2et*128 interleaved (katt,vmsg)
#define M_PER_T (64 * M_COLS)              // 20480 floats per type
#define PCH 50                             // proj: type-list entries per block
#define OCH 100                            // out: type-list entries per block
#define LOG2E 1.44269504088896f

__device__ __forceinline__ unsigned int f32_to_bf16(float f) {
  unsigned int u = __float_as_uint(f);
  return (u + 0x7FFFu + ((u >> 16) & 1u)) >> 16;   // RNE
}

// ---------------------------------------------------------------------------
// Prep kernel (merged): fold weights into COLUMN-MAJOR M2 + transpose Wa ->
// Wa2 + zero deg/tcnt.
//   M2[t][col][k] (k contiguous): col 0..63 -> q; col 64+cc: et=cc>>7,
//   r=cc&127, c=r>>1, half=r&1 -> half0: katt[et][n][c], half1: vmsg[et][n][c]
//   Wa2[t][col][k] = Wa[t][k][col]
// ---------------------------------------------------------------------------
__global__ void prep_kernel(const float* __restrict__ Wk,
                            const float* __restrict__ Wq,
                            const float* __restrict__ Wv,
                            const float* __restrict__ Wa,
                            const float* __restrict__ Ratt,
                            const float* __restrict__ Rmsg,
                            float* __restrict__ M2, float* __restrict__ Wa2,
                            int* __restrict__ deg, int* __restrict__ tcnt) {
  int idx = blockIdx.x * 256 + threadIdx.x;
  if (idx < N_NODES) deg[idx] = 0;
  if (idx < NT_TYPES) tcnt[idx] = 0;
  if (idx < NT_TYPES * 4096) {              // Wa transpose
    int t = idx >> 12;
    int rem = idx & 4095;
    int col = rem >> 6, k = rem & 63;
    Wa2[idx] = Wa[(size_t)t * 4096 + k * 64 + col];
  }
  if (idx < NT_TYPES * M_PER_T) {
    int t = idx / M_PER_T;
    int rem = idx % M_PER_T;
    int col = rem / 64;                     // column-major: k contiguous
    int k = rem % 64;
    float val;
    if (col < 64) {
      val = Wq[(size_t)t * 4096 + k * 64 + col];
    } else {
      int cc = col - 64;
      int et = cc >> 7;
      int r = cc & 127;
      int c = r >> 1;
      int half = r & 1;
      int h = c >> 4, f = c & 15;
      const float* W = half ? Wv : Wk;
      const float* R = half ? Rmsg : Ratt;
      float s = 0.f;
#pragma unroll
      for (int d = 0; d < 16; ++d)
        s = fmaf(W[(size_t)t * 4096 + k * 64 + h * 16 + d],
                 R[(((size_t)h * ET_TYPES + et) * 16 + d) * 16 + f], s);
      val = s;
    }
    M2[idx] = val;
  }
}

// ---------------------------------------------------------------------------
// Build kernel (merged): edge-parallel degree count + node-parallel type
// lists with per-block LDS aggregation (one global atomic per block,type).
// ---------------------------------------------------------------------------
__global__ void build_kernel(const int* __restrict__ dst,
                             const int* __restrict__ ntype,
                             int* __restrict__ deg, int* __restrict__ tcnt,
                             int* __restrict__ tlist) {
  const int e = blockIdx.x * 256 + threadIdx.x;
  if (e < N_EDGES) atomicAdd(&deg[dst[e]], 1);
  if (blockIdx.x < NB_SCAN) {
    __shared__ int lcnt[NT_TYPES];
    __shared__ int lbase[NT_TYPES];
    if (threadIdx.x < NT_TYPES) lcnt[threadIdx.x] = 0;
    __syncthreads();
    int t = 0, lpos = 0;
    const bool valid = (e < N_NODES);
    if (valid) {
      t = ntype[e];
      lpos = atomicAdd(&lcnt[t], 1);        // LDS atomic
    }
    __syncthreads();
    if (threadIdx.x < NT_TYPES)
      lbase[threadIdx.x] = atomicAdd(&tcnt[threadIdx.x], lcnt[threadIdx.x]);
    __syncthreads();
    if (valid)
      tlist[t * N_NODES + lbase[t] + lpos] = e;
  }
}

// ---------------------------------------------------------------------------
// Fused projection over type-lists: thread = output column; weight column in
// 16 float4 VGPRs (R9 lesson: __launch_bounds__ min-waves arg caps VGPRs at
// ~C/minwaves -> (320,4) gave 40 VGPR and scratch-spilled wcol; use (320,1)).
// Node index via readfirstlane -> x row as uniform float4 s_loads.
// ---------------------------------------------------------------------------
__device__ __forceinline__ void proj_store(int w, int lane, int col, int n,
                                           float acc, float* __restrict__ q,
                                           unsigned int* __restrict__ kvb) {
  if (w == 0) {
    q[(size_t)n * 64 + lane] = acc;
  } else {
    float part = __shfl_xor(acc, 1, 64);   // partner column's value
    if ((lane & 1) == 0) {                 // even = katt, partner = vmsg
      int cc = col - 64;                   // 0..255, even
      int et = cc >> 7;
      int c = (cc & 127) >> 1;             // feature 0..63
      unsigned int word = f32_to_bf16(acc) | (f32_to_bf16(part) << 16);
      kvb[((size_t)et * N_NODES + n) * 64 + c] = word;
    }
  }
}

__global__ __launch_bounds__(320, 1) void fused_proj_kernel(
    const float* __restrict__ x, const float* __restrict__ M2,
    const int* __restrict__ tcnt, const int* __restrict__ tlist,
    float* __restrict__ q, unsigned int* __restrict__ kvb) {
  const int w = threadIdx.x >> 6;
  const int lane = threadIdx.x & 63;
  const int col = threadIdx.x;
  const int ty = blockIdx.y;

  const int cnt = __builtin_amdgcn_readfirstlane(tcnt[ty]);
  const int i0 = blockIdx.x * PCH;
  if (i0 >= cnt) return;
  const int i1 = min(i0 + PCH, cnt);

  const float4* wsrc = reinterpret_cast<const float4*>(
      M2 + ((size_t)ty * M_COLS + col) * 64);
  float4 W[16];
#pragma unroll
  for (int j = 0; j < 16; ++j) W[j] = wsrc[j];

  const int* lst = tlist + ty * N_NODES;

  for (int i = i0; i < i1; ++i) {
    const int n = __builtin_amdgcn_readfirstlane(lst[i]);
    const float4* xr4 = reinterpret_cast<const float4*>(x + (size_t)n * 64);
    float a0 = 0.f, a1 = 0.f, a2 = 0.f, a3 = 0.f;
#pragma unroll
    for (int j = 0; j < 16; ++j) {
      float4 xa = xr4[j];                  // uniform -> s_load_dwordx4
      a0 = fmaf(xa.x, W[j].x, a0);
      a1 = fmaf(xa.y, W[j].y, a1);
      a2 = fmaf(xa.z, W[j].z, a2);
      a3 = fmaf(xa.w, W[j].w, a3);
    }
    proj_store(w, lane, col, n, (a0 + a1) + (a2 + a3), q, kvb);
  }
}

// ---------------------------------------------------------------------------
// CSR build: 3-kernel scan + fill packed edge records.
// ---------------------------------------------------------------------------
__global__ void block_sums_kernel(const int* __restrict__ deg, int* __restrict__ bsums) {
  __shared__ int sh[256];
  int i = blockIdx.x * 256 + threadIdx.x;
  sh[threadIdx.x] = (i < N_NODES) ? deg[i] : 0;
  __syncthreads();
  for (int off = 128; off > 0; off >>= 1) {
    if (threadIdx.x < off) sh[threadIdx.x] += sh[threadIdx.x + off];
    __syncthreads();
  }
  if (threadIdx.x == 0) bsums[blockIdx.x] = sh[0];
}

__global__ void scan_sums_kernel(int* __restrict__ bsums) {
  __shared__ int sh[256];
  int t = threadIdx.x;
  sh[t] = (t < NB_SCAN) ? bsums[t] : 0;
  __syncthreads();
  for (int off = 1; off < 256; off <<= 1) {
    int v = (t >= off) ? sh[t - off] : 0;
    __syncthreads();
    sh[t] += v;
    __syncthreads();
  }
  if (t < NB_SCAN) bsums[t] = (t ? sh[t - 1] : 0);  // exclusive
}

__global__ void scan_final_kernel(const int* __restrict__ deg, const int* __restrict__ bsums,
                                  int* __restrict__ rowstart, int* __restrict__ cursor) {
  __shared__ int sh[256];
  int i = blockIdx.x * 256 + threadIdx.x;
  int t = threadIdx.x;
  sh[t] = (i < N_NODES) ? deg[i] : 0;
  __syncthreads();
  for (int off = 1; off < 256; off <<= 1) {
    int v = (t >= off) ? sh[t - off] : 0;
    __syncthreads();
    sh[t] += v;
    __syncthreads();
  }
  if (i < N_NODES) {
    int excl = (t ? sh[t - 1] : 0) + bsums[blockIdx.x];
    rowstart[i] = excl;
    cursor[i] = excl;
  }
}

// csr record: ((et*N + src) << 7) | et   -> kvb index = pk>>1, et = pk&1
__global__ void fill_csr_kernel(const int* __restrict__ src, const int* __restrict__ dst,
                                const int* __restrict__ etype, int* __restrict__ cursor,
                                int* __restrict__ csr) {
  int e = blockIdx.x * 256 + threadIdx.x;
  if (e < N_EDGES) {
    int d = dst[e];
    int et = etype[e];
    int pos = atomicAdd(&cursor[d], 1);
    csr[pos] = ((et * N_NODES + src[e]) << 7) | et;
  }
}

// ---------------------------------------------------------------------------
// Aggregation: per-dst-node exp-sum softmax (no max subtraction -- logits are
// O(0.1), mathematically identical). Node/csr control path scalarized via
// readfirstlane. Writes h into hsg (aliases q: q[n] read only by node-n's
// own wave, before its write). No LDS, no syncthreads.
// ---------------------------------------------------------------------------
__device__ __forceinline__ void edge_update(unsigned int wrd, int et, float qd,
                                            float s0, float s1,
                                            float& srun, float& acc) {
  float kw = __uint_as_float(wrd << 16);            // low bf16 = katt
  float mv = __uint_as_float(wrd & 0xFFFF0000u);    // high bf16 = vmsg
  float p = kw * qd;
  p += __shfl_xor(p, 1, 16);
  p += __shfl_xor(p, 2, 16);
  p += __shfl_xor(p, 4, 16);
  p += __shfl_xor(p, 8, 16);
  float w = __builtin_amdgcn_exp2f(p * (et ? s1 : s0));  // exp(a) via v_exp
  srun += w;
  acc = fmaf(mv, w, acc);
}

__global__ __launch_bounds__(256) void aggregate_kernel(
    const float* __restrict__ q, const unsigned int* __restrict__ kvb,
    const float* __restrict__ pri, const int* __restrict__ rowstart,
    const int* __restrict__ deg, const int* __restrict__ csr,
    float* __restrict__ hsg) {
  const int wave = threadIdx.x >> 6;
  const int lane = threadIdx.x & 63;
  int n = blockIdx.x * 4 + wave;
  if (n >= N_NODES) return;
  n = __builtin_amdgcn_readfirstlane(n);

  const int hh = lane >> 4;
  const float qd = q[(size_t)n * 64 + lane];
  const float s0 = pri[hh * ET_TYPES + 0] * 0.25f * LOG2E;
  const float s1 = pri[hh * ET_TYPES + 1] * 0.25f * LOG2E;
  const int start = __builtin_amdgcn_readfirstlane(rowstart[n]);
  const int cnt = __builtin_amdgcn_readfirstlane(deg[n]);
  const int* crow = csr + start;

  float srun = 0.f, acc = 0.f;
  int j = 0;
  for (; j + 8 <= cnt; j += 8) {
    int pk0 = __builtin_amdgcn_readfirstlane(crow[j + 0]);
    int pk1 = __builtin_amdgcn_readfirstlane(crow[j + 1]);
    int pk2 = __builtin_amdgcn_readfirstlane(crow[j + 2]);
    int pk3 = __builtin_amdgcn_readfirstlane(crow[j + 3]);
    int pk4 = __builtin_amdgcn_readfirstlane(crow[j + 4]);
    int pk5 = __builtin_amdgcn_readfirstlane(crow[j + 5]);
    int pk6 = __builtin_amdgcn_readfirstlane(crow[j + 6]);
    int pk7 = __builtin_amdgcn_readfirstlane(crow[j + 7]);
    unsigned int w0 = kvb[((unsigned)pk0 >> 1) + lane];
    unsigned int w1 = kvb[((unsigned)pk1 >> 1) + lane];
    unsigned int w2 = kvb[((unsigned)pk2 >> 1) + lane];
    unsigned int w3 = kvb[((unsigned)pk3 >> 1) + lane];
    unsigned int w4 = kvb[((unsigned)pk4 >> 1) + lane];
    unsigned int w5 = kvb[((unsigned)pk5 >> 1) + lane];
    unsigned int w6 = kvb[((unsigned)pk6 >> 1) + lane];
    unsigned int w7 = kvb[((unsigned)pk7 >> 1) + lane];
    edge_update(w0, pk0 & 1, qd, s0, s1, srun, acc);
    edge_update(w1, pk1 & 1, qd, s0, s1, srun, acc);
    edge_update(w2, pk2 & 1, qd, s0, s1, srun, acc);
    edge_update(w3, pk3 & 1, qd, s0, s1, srun, acc);
    edge_update(w4, pk4 & 1, qd, s0, s1, srun, acc);
    edge_update(w5, pk5 & 1, qd, s0, s1, srun, acc);
    edge_update(w6, pk6 & 1, qd, s0, s1, srun, acc);
    edge_update(w7, pk7 & 1, qd, s0, s1, srun, acc);
  }
  for (; j + 4 <= cnt; j += 4) {
    int pk0 = __builtin_amdgcn_readfirstlane(crow[j + 0]);
    int pk1 = __builtin_amdgcn_readfirstlane(crow[j + 1]);
    int pk2 = __builtin_amdgcn_readfirstlane(crow[j + 2]);
    int pk3 = __builtin_amdgcn_readfirstlane(crow[j + 3]);
    unsigned int w0 = kvb[((unsigned)pk0 >> 1) + lane];
    unsigned int w1 = kvb[((unsigned)pk1 >> 1) + lane];
    unsigned int w2 = kvb[((unsigned)pk2 >> 1) + lane];
    unsigned int w3 = kvb[((unsigned)pk3 >> 1) + lane];
    edge_update(w0, pk0 & 1, qd, s0, s1, srun, acc);
    edge_update(w1, pk1 & 1, qd, s0, s1, srun, acc);
    edge_update(w2, pk2 & 1, qd, s0, s1, srun, acc);
    edge_update(w3, pk3 & 1, qd, s0, s1, srun, acc);
  }
  for (; j < cnt; ++j) {
    int pk = __builtin_amdgcn_readfirstlane(crow[j]);
    unsigned int wd = kvb[((unsigned)pk >> 1) + lane];
    edge_update(wd, pk & 1, qd, s0, s1, srun, acc);
  }
  hsg[(size_t)n * 64 + lane] = (srun > 0.f) ? (acc / srun) : 0.f;
}

// ---------------------------------------------------------------------------
// Output kernel over type-lists: Wa2 column in 16 float4 VGPRs ((256,1) --
// same launch-bounds lesson), one wave per node, h row via uniform s_loads.
// ---------------------------------------------------------------------------
__global__ __launch_bounds__(256, 1) void out_kernel(
    const float* __restrict__ hsg, const float* __restrict__ x,
    const float* __restrict__ Wa2, const float* __restrict__ skip,
    const int* __restrict__ tcnt, const int* __restrict__ tlist,
    float* __restrict__ out) {
  const int w = threadIdx.x >> 6;
  const int lane = threadIdx.x & 63;
  const int ty = blockIdx.y;

  const int cnt = __builtin_amdgcn_readfirstlane(tcnt[ty]);
  const int base = blockIdx.x * OCH;
  if (base >= cnt) return;
  const int iend = min(base + OCH, cnt);

  const float4* wsrc = reinterpret_cast<const float4*>(
      Wa2 + ((size_t)ty * 64 + lane) * 64);
  float4 W[16];
#pragma unroll
  for (int j = 0; j < 16; ++j) W[j] = wsrc[j];

  const float alpha = 1.f / (1.f + __expf(-skip[ty]));
  const float beta = 1.f - alpha;
  const int* lst = tlist + ty * N_NODES;

  for (int i = base + w; i < iend; i += 4) {
    const int n = __builtin_amdgcn_readfirstlane(lst[i]);
    const float4* hr4 = reinterpret_cast<const float4*>(hsg + (size_t)n * 64);
    float a0 = 0.f, a1 = 0.f, a2 = 0.f, a3 = 0.f;
#pragma unroll
    for (int j = 0; j < 16; ++j) {
      float4 ha = hr4[j];                  // uniform -> s_load_dwordx4
      a0 = fmaf(ha.x, W[j].x, a0);
      a1 = fmaf(ha.y, W[j].y, a1);
      a2 = fmaf(ha.z, W[j].z, a2);
      a3 = fmaf(ha.w, W[j].w, a3);
    }
    size_t o = (size_t)n * 64 + lane;
    out[o] = ((a0 + a1) + (a2 + a3)) * alpha + x[o] * beta;
  }
}

// ---------------------------------------------------------------------------
extern "C" void kernel_launch(void* const* d_in, const int* in_sizes, int n_in,
                              void* d_out, int out_size, void* d_ws, size_t ws_size,
                              hipStream_t stream) {
  const float* x    = (const float*)d_in[0];
  const float* Wk   = (const float*)d_in[1];
  const float* Wq   = (const float*)d_in[2];
  const float* Wv   = (const float*)d_in[3];
  const float* Wa   = (const float*)d_in[4];
  const float* Ratt = (const float*)d_in[5];
  const float* Rmsg = (const float*)d_in[6];
  const float* pri  = (const float*)d_in[7];
  const float* skip = (const float*)d_in[8];
  const int* ntype  = (const int*)d_in[9];
  const int* etype  = (const int*)d_in[10];
  const int* src    = (const int*)d_in[11];
  const int* dst    = (const int*)d_in[12];
  float* out = (float*)d_out;

  // workspace layout
  float* q     = (float*)d_ws;                          // N*64 floats (also hsg)
  unsigned int* kvb = (unsigned int*)(q + (size_t)N_NODES * 64);  // ET*N*64 dwords
  int* rowstart = (int*)(kvb + (size_t)ET_TYPES * N_NODES * 64);  // N
  int* deg      = rowstart + N_NODES;                   // N
  int* tcnt     = deg + N_NODES;                        // 2
  int* cursor   = tcnt + 2;                             // N
  int* tlist    = cursor + N_NODES;                     // 2*N
  int* csr      = tlist + 2 * N_NODES;                  // E
  int* bsums    = csr + N_EDGES;                        // NB_SCAN (<=256)
  float* M2     = (float*)(((uintptr_t)(bsums + 256) + 255) & ~(uintptr_t)255);
  float* Wa2    = M2 + (size_t)NT_TYPES * M_PER_T;      // NT*64*64 (256B-aligned)
  float* hsg    = q;                                    // alias (safe, see agg)

  prep_kernel<<<NB_SCAN, 256, 0, stream>>>(Wk, Wq, Wv, Wa, Ratt, Rmsg,
                                           M2, Wa2, deg, tcnt);

  build_kernel<<<(N_EDGES + 255) / 256, 256, 0, stream>>>(
      dst, ntype, deg, tcnt, tlist);

  dim3 pgrid((N_NODES + PCH - 1) / PCH, NT_TYPES);
  fused_proj_kernel<<<pgrid, 320, 0, stream>>>(x, M2, tcnt, tlist, q, kvb);

  block_sums_kernel<<<NB_SCAN, 256, 0, stream>>>(deg, bsums);
  scan_sums_kernel<<<1, 256, 0, stream>>>(bsums);
  scan_final_kernel<<<NB_SCAN, 256, 0, stream>>>(deg, bsums, rowstart, cursor);
  fill_csr_kernel<<<(N_EDGES + 255) / 256, 256, 0, stream>>>(src, dst, etype, cursor, csr);

  aggregate_kernel<<<(N_NODES + 3) / 4, 256, 0, stream>>>(
      (const float*)q, (const unsigned int*)kvb, pri, rowstart, deg, csr, hsg);

  dim3 ogrid((N_NODES + OCH - 1) / OCH, NT_TYPES);
  out_kernel<<<ogrid, 256, 0, stream>>>(hsg, x, Wa2, skip, tcnt, tlist, out);
}